// Round 6
// baseline (192.870 us; speedup 1.0000x reference)
//
#include <hip/hip_runtime.h>
#include <stdint.h>

#define NHEADS 16
#define DHEAD 64
#define SEQ 2048
#define BATCH 2
#define NINF 1024
#define NOUTF 1024
#define N3 3072
#define MTOT 4096  // BATCH*SEQ

typedef unsigned short US;
typedef __attribute__((ext_vector_type(8))) short short8;
typedef __attribute__((ext_vector_type(4))) short short4v;
typedef __attribute__((ext_vector_type(4))) float f32x4;

__device__ inline US f2bf(float f) {
  union { float f; unsigned u; } v; v.f = f;
  unsigned r = v.u + 0x7fffu + ((v.u >> 16) & 1u);
  return (US)(r >> 16);
}

__device__ inline f32x4 mfma16(short8 a, short8 b, f32x4 c) {
  return __builtin_amdgcn_mfma_f32_16x16x32_bf16(a, b, c, 0, 0, 0);
}

__device__ inline f32x4 mfma16k16(short4v a, short4v b, f32x4 c) {
  return __builtin_amdgcn_mfma_f32_16x16x16bf16_1k(a, b, c, 0, 0, 0);
}

__device__ inline void async16(const US* g, US* l) {
  __builtin_amdgcn_global_load_lds(
      (const __attribute__((address_space(1))) unsigned int*)g,
      (__attribute__((address_space(3))) unsigned int*)l, 16, 0, 0);
}

// fp32 -> bf16, 4 elements/thread
__global__ void k_convert(const float* __restrict__ src, US* __restrict__ dst, int n4) {
  int i = blockIdx.x * blockDim.x + threadIdx.x;
  if (i >= n4) return;
  float4 v = ((const float4*)src)[i];
  ushort4 o;
  o.x = f2bf(v.x); o.y = f2bf(v.y); o.z = f2bf(v.z); o.w = f2bf(v.w);
  ((ushort4*)dst)[i] = o;
}

// merged weight transpose: Wqkv [1024][3072] and Wff [1024][1024] -> bf16 [C][1024]
__global__ void k_wtrans(const float* __restrict__ Wqkv, const float* __restrict__ Wff,
                         US* __restrict__ dq, US* __restrict__ df) {
  __shared__ float tile[32][33];
  int bxi = blockIdx.x;
  const float* src; US* dst; int C;
  if (bxi < 96) { src = Wqkv; dst = dq; C = N3; }
  else          { src = Wff;  dst = df; C = NOUTF; bxi -= 96; }
  int bx = bxi * 32, by = blockIdx.y * 32;
  int tx = threadIdx.x, ty = threadIdx.y;
  for (int i = 0; i < 32; i += 8)
    tile[ty + i][tx] = src[(size_t)(by + ty + i) * C + bx + tx];
  __syncthreads();
  for (int i = 0; i < 32; i += 8)
    dst[(size_t)(bx + ty + i) * 1024 + by + tx] = f2bf(tile[tx][ty + i]);
}

// ---------------- qkv GEMM v2: 128x128 tile, orientation-aware epilogue ----
// v11: MFMA C-layout is row(M)=lk*4+r, col(N)=lm. Swapping operand order
// (mfma(b,a)) transposes the output tile for FREE (A/B fragments have the
// same lane layout), making reg index r walk the OUTPUT COLUMN (d):
//  - Q/K blocks: swapped -> one contiguous uint2 (4 bf16 along d) per (i,j):
//    16 stores/thread instead of 64 scalar 2B stores, 512B/instr effective.
//  - V blocks (which==2, block-uniform): UNSWAPPED -> r walks rows = seq,
//    which is vtbuf's [bh][d][s] contiguous axis: write vtbuf DIRECTLY.
//    k_vtrans deleted (-16MB HBM round trip, -1 launch).
// FP math bit-identical (same dot products, same order).
__global__ __launch_bounds__(256) void k_gemm_qkv(
    const US* __restrict__ A,   // [MTOT][NINF]
    const US* __restrict__ Bt,  // [N3][NINF]
    US* __restrict__ qbuf, US* __restrict__ kbuf, US* __restrict__ vtbuf) {
  __shared__ US As[128 * 32];
  __shared__ US Bs[128 * 32];
  int tid = threadIdx.x;
  int wave = tid >> 6, lane = tid & 63, lm = lane & 15, lk = lane >> 4;
  int wm = wave >> 1, wn = wave & 1;
  int mbase = blockIdx.y * 128, nbase = blockIdx.x * 128;
  int which = nbase >> 10;  // 0=q 1=k 2=v (uniform per block)

  f32x4 acc[4][4];
#pragma unroll
  for (int i = 0; i < 4; ++i)
#pragma unroll
    for (int j = 0; j < 4; ++j) acc[i][j] = (f32x4){0.f, 0.f, 0.f, 0.f};

  const US* ga = A + (size_t)(mbase + (tid >> 2)) * NINF + (tid & 3) * 8;
  const US* gb = Bt + (size_t)(nbase + (tid >> 2)) * NINF + (tid & 3) * 8;
  US* la = As + tid * 8;
  US* lb = Bs + tid * 8;

  for (int kt = 0; kt < NINF / 32; ++kt) {
    int ko = kt * 32;
    async16(ga + ko, la);
    async16(ga + ko + (size_t)64 * NINF, la + 64 * 32);
    async16(gb + ko, lb);
    async16(gb + ko + (size_t)64 * NINF, lb + 64 * 32);
    __syncthreads();
    short8 a[4], b[4];
#pragma unroll
    for (int i = 0; i < 4; ++i)
      a[i] = *(const short8*)(As + (wm * 64 + i * 16 + lm) * 32 + lk * 8);
#pragma unroll
    for (int j = 0; j < 4; ++j)
      b[j] = *(const short8*)(Bs + (wn * 64 + j * 16 + lm) * 32 + lk * 8);
    if (which != 2) {
      // swapped: lane holds C[m=mbase+wm*64+i*16+lm][n=nbase+wn*64+j*16+lk*4+r]
#pragma unroll
      for (int i = 0; i < 4; ++i)
#pragma unroll
        for (int j = 0; j < 4; ++j) acc[i][j] = mfma16(b[j], a[i], acc[i][j]);
    } else {
      // unswapped: lane holds C[m=mbase+wm*64+i*16+lk*4+r][n=nbase+wn*64+j*16+lm]
#pragma unroll
      for (int i = 0; i < 4; ++i)
#pragma unroll
        for (int j = 0; j < 4; ++j) acc[i][j] = mfma16(a[i], b[j], acc[i][j]);
    }
    __syncthreads();
  }

  int hh = ((nbase + wn * 64) & 1023) >> 6;  // head of this wave's 64-col block
  if (which != 2) {
    US* dsts = (which == 0) ? qbuf : kbuf;
    float sc = (which == 0) ? 0.18033688011112042f : 1.f;  // log2(e)/8 folded into Q
#pragma unroll
    for (int i = 0; i < 4; ++i) {
      int row = mbase + wm * 64 + i * 16 + lm;
      int bh = (row >> 11) * NHEADS + hh;
      int s = row & (SEQ - 1);
      US* base = dsts + ((size_t)bh * SEQ + s) * DHEAD;
#pragma unroll
      for (int j = 0; j < 4; ++j) {
        int d0 = j * 16 + lk * 4;
        uint32_t lo = (uint32_t)f2bf(acc[i][j][0] * sc) | ((uint32_t)f2bf(acc[i][j][1] * sc) << 16);
        uint32_t hi = (uint32_t)f2bf(acc[i][j][2] * sc) | ((uint32_t)f2bf(acc[i][j][3] * sc) << 16);
        uint2 pv; pv.x = lo; pv.y = hi;
        *(uint2*)(base + d0) = pv;   // 8B contiguous along d
      }
    }
  } else {
    // direct V^T write: vtbuf [bh][d][s], r walks s (contiguous)
#pragma unroll
    for (int j = 0; j < 4; ++j) {
      int d = j * 16 + lm;
#pragma unroll
      for (int i = 0; i < 4; ++i) {
        int row0 = mbase + wm * 64 + i * 16 + lk * 4;
        int bh = (row0 >> 11) * NHEADS + hh;
        int s0 = row0 & (SEQ - 1);
        uint32_t lo = (uint32_t)f2bf(acc[i][j][0]) | ((uint32_t)f2bf(acc[i][j][1]) << 16);
        uint32_t hi = (uint32_t)f2bf(acc[i][j][2]) | ((uint32_t)f2bf(acc[i][j][3]) << 16);
        uint2 pv; pv.x = lo; pv.y = hi;
        *(uint2*)(vtbuf + ((size_t)bh * DHEAD + d) * SEQ + s0) = pv;  // 8B along s
      }
    }
  }
}

// ---------------- attention v8 (reverted best: 45.7us) ----------------
// v9 (full key-split) regressed 64.8; v10 (hybrid 32q x 32k) neutral 46.5 with
// halved conflicts -> LDS throughput proven NOT the critical path. v8 is the
// local optimum of this structure: q-split waves, balanced dispatch rounds,
// depth-2 dbuf + counted vmcnt(4), ones-MFMA rowsums, exp2-domain scores.
__global__ __launch_bounds__(256) void k_attn(
    const US* __restrict__ qbuf, const US* __restrict__ kbuf,
    const US* __restrict__ vtbuf, US* __restrict__ ctx) {
  __shared__ US Ks[2][64 * 64];
  __shared__ US Vs[2][64 * 64];
  int tid = threadIdx.x;
  int w = tid >> 6, lane = tid & 63;
  int lm = lane & 15, lk = lane >> 4;
  int bl = blockIdx.x;            // 1024 blocks
  int xcd = bl & 7, g = bl >> 3;  // g 0..127
  int bh = (g & 3) * 8 + xcd;     // 4 bh per XCD -> working set ~2MB < 4MB L2
  int q4 = g >> 2;                // 0..31
  int rnd = q4 >> 3, qq = q4 & 7;
  int s = (rnd == 0) ? 31 - qq : (rnd == 1) ? qq : (rnd == 2) ? 23 - qq : 8 + qq;
  int qb = s * 64 + w * 16;
  int nt = s + 1;                 // 64-key tiles (can be 1)

  const US* kbase = kbuf + (size_t)bh * SEQ * DHEAD;
  const US* vtb = vtbuf + (size_t)bh * DHEAD * SEQ;
  const US* qr = qbuf + ((size_t)bh * SEQ + qb + lm) * DHEAD + lk * 8;
  short8 qf0 = *(const short8*)(qr);
  short8 qf1 = *(const short8*)(qr + 32);

  // staging: 16 async16 units (8 K + 8 V), 4 per wave, source-side XOR swizzle
  int swz = ((lane & 7) ^ (lane >> 3)) * 8;
  const US* gsrc[4];
  US* ldst[4];
  int step[4];
#pragma unroll
  for (int j = 0; j < 4; ++j) {
    int u = w + 4 * j;
    if (u < 8) {
      gsrc[j] = kbase + (size_t)(u * 8 + (lane >> 3)) * DHEAD + swz;
      ldst[j] = &Ks[0][0] + u * 512 + lane * 8;
      step[j] = 64 * DHEAD;
    } else {
      int i = u - 8;
      gsrc[j] = vtb + (size_t)(i * 8 + (lane >> 3)) * SEQ + swz;
      ldst[j] = &Vs[0][0] + i * 512 + lane * 8;
      step[j] = 64;
    }
  }

  // fragment-read offsets (bytes), swizzle-corrected
  int xorv = lm & 7;
  int ck0 = ((lk) ^ xorv) * 16;
  int ck1 = ((4 + lk) ^ xorv) * 16;
  int cv[4];
#pragma unroll
  for (int kg = 0; kg < 4; ++kg)
    cv[kg] = (((kg * 2 + (lk >> 1)) ^ xorv) * 16) + (lk & 1) * 8;

  f32x4 o[4];
#pragma unroll
  for (int dg = 0; dg < 4; ++dg) o[dg] = (f32x4){0.f, 0.f, 0.f, 0.f};
  f32x4 lacc = (f32x4){0.f, 0.f, 0.f, 0.f};
  const short4v kones = {(short)0x3F80, (short)0x3F80, (short)0x3F80, (short)0x3F80};

  auto body = [&](const char* Kc, const char* Vc, int kg, bool dm) {
    const char* kr = Kc + (kg * 16 + lm) * 128;
    short8 ka0 = *(const short8*)(kr + ck0);
    short8 ka1 = *(const short8*)(kr + ck1);
    f32x4 st = (f32x4){0.f, 0.f, 0.f, 0.f};
    st = mfma16(ka0, qf0, st);
    st = mfma16(ka1, qf1, st);
    uint32_t ue[4];
#pragma unroll
    for (int r = 0; r < 4; ++r) {
      float v = st[r];                       // already in log2 domain (Q pre-scaled)
      if (dm && (lk * 4 + r > lm)) v = -INFINITY;
      union { float f; uint32_t u; } cv2;
      cv2.f = exp2f(v);
      ue[r] = cv2.u + 0x8000u;               // bf16 bias-round; -inf path -> 0x8000 -> +0
    }
    union { short4v s4; uint32_t u[2]; } pk;
    pk.u[0] = __builtin_amdgcn_perm(ue[1], ue[0], 0x07060302u);
    pk.u[1] = __builtin_amdgcn_perm(ue[3], ue[2], 0x07060302u);
    lacc = mfma16k16(kones, pk.s4, lacc);    // row-sums on the MFMA pipe
    const char* vr = Vc + lm * 128 + cv[kg];
#pragma unroll
    for (int dg = 0; dg < 4; ++dg) {
      short4v va = *(const short4v*)(vr + dg * 2048);
      o[dg] = mfma16k16(va, pk.s4, o[dg]);
    }
  };

  // prologue: tile0 -> buf0, (tile1 -> buf1 if it exists)
#pragma unroll
  for (int j = 0; j < 4; ++j) { async16(gsrc[j], ldst[j]); gsrc[j] += step[j]; }
  if (nt > 1) {
#pragma unroll
    for (int j = 0; j < 4; ++j) { async16(gsrc[j], ldst[j] + 4096); gsrc[j] += step[j]; }
  }

  for (int t = 0; t < nt; ++t) {
    if (t + 1 < nt) asm volatile("s_waitcnt vmcnt(4)" ::: "memory");
    else            asm volatile("s_waitcnt vmcnt(0)" ::: "memory");
    __builtin_amdgcn_s_barrier();
    asm volatile("" ::: "memory");
    const char* Kc = (const char*)Ks + (t & 1) * 8192;
    const char* Vc = (const char*)Vs + (t & 1) * 8192;
    if (t < s) {
#pragma unroll
      for (int kg = 0; kg < 4; ++kg) body(Kc, Vc, kg, false);
    } else {
      // diagonal tile: kg > w fully masked, kg == w partially
      for (int kg = 0; kg < w; ++kg) body(Kc, Vc, kg, false);
      body(Kc, Vc, w, true);
    }
    asm volatile("" ::: "memory");
    __builtin_amdgcn_s_barrier();
    asm volatile("" ::: "memory");
    if (t + 2 < nt) {
#pragma unroll
      for (int j = 0; j < 4; ++j) {
        async16(gsrc[j], ldst[j] + (t & 1) * 4096);
        gsrc[j] += step[j];
      }
    }
  }

  // lacc[*] = rowsum for q-row lm (identical across regs/lk groups)
  float inv = 1.f / lacc[0];

  US* crow = ctx + ((size_t)(bh >> 4) * SEQ + qb + lm) * NOUTF + (bh & 15) * DHEAD;
#pragma unroll
  for (int dg = 0; dg < 4; ++dg) {
    union { short4v s4; uint32_t u[2]; } pk;
    pk.u[0] = (uint32_t)f2bf(o[dg][0] * inv) | ((uint32_t)f2bf(o[dg][1] * inv) << 16);
    pk.u[1] = (uint32_t)f2bf(o[dg][2] * inv) | ((uint32_t)f2bf(o[dg][3] * inv) << 16);
    *(short4v*)(crow + dg * 16 + lk * 4) = pk.s4;
  }
}

// ---------------- out GEMM v2: 128x64 tile, swapped epilogue, float4 out ----
// Same orientation trick: mfma(b,a) -> r walks output column. One float4
// store (bias fused via float4 load) per (i,j): 8 stores/thread vs 32.
__global__ __launch_bounds__(256) void k_gemm_out(
    const US* __restrict__ A, const US* __restrict__ Bt,
    const float* __restrict__ bias, float* __restrict__ out) {
  __shared__ US As[128 * 32];
  __shared__ US Bs[64 * 32];
  int tid = threadIdx.x;
  int wave = tid >> 6, lane = tid & 63, lm = lane & 15, lk = lane >> 4;
  int mbase = blockIdx.y * 128, nbase = blockIdx.x * 64;

  f32x4 acc[2][4];
#pragma unroll
  for (int i = 0; i < 2; ++i)
#pragma unroll
    for (int j = 0; j < 4; ++j) acc[i][j] = (f32x4){0.f, 0.f, 0.f, 0.f};

  const US* ga = A + (size_t)(mbase + (tid >> 2)) * NOUTF + (tid & 3) * 8;
  const US* gb = Bt + (size_t)(nbase + (tid >> 2)) * NOUTF + (tid & 3) * 8;
  US* la = As + tid * 8;
  US* lb = Bs + tid * 8;

  for (int kt = 0; kt < NOUTF / 32; ++kt) {
    int ko = kt * 32;
    async16(ga + ko, la);
    async16(ga + ko + (size_t)64 * NOUTF, la + 64 * 32);
    async16(gb + ko, lb);
    __syncthreads();
    short8 a[2], b[4];
#pragma unroll
    for (int i = 0; i < 2; ++i)
      a[i] = *(const short8*)(As + (wave * 32 + i * 16 + lm) * 32 + lk * 8);
#pragma unroll
    for (int j = 0; j < 4; ++j)
      b[j] = *(const short8*)(Bs + (j * 16 + lm) * 32 + lk * 8);
    // swapped: lane holds out[m=mbase+wave*32+i*16+lm][n=nbase+j*16+lk*4+r]
#pragma unroll
    for (int i = 0; i < 2; ++i)
#pragma unroll
      for (int j = 0; j < 4; ++j) acc[i][j] = mfma16(b[j], a[i], acc[i][j]);
    __syncthreads();
  }

#pragma unroll
  for (int j = 0; j < 4; ++j) {
    int n0 = nbase + j * 16 + lk * 4;
    float4 bv = *(const float4*)(bias + n0);
#pragma unroll
    for (int i = 0; i < 2; ++i) {
      int row = mbase + wave * 32 + i * 16 + lm;
      float4 ov;
      ov.x = acc[i][j][0] + bv.x;
      ov.y = acc[i][j][1] + bv.y;
      ov.z = acc[i][j][2] + bv.z;
      ov.w = acc[i][j][3] + bv.w;
      *(float4*)(out + (size_t)row * NOUTF + n0) = ov;  // 16B contiguous
    }
  }
}

extern "C" void kernel_launch(void* const* d_in, const int* in_sizes, int n_in,
                              void* d_out, int out_size, void* d_ws, size_t ws_size,
                              hipStream_t stream) {
  const float* y    = (const float*)d_in[0];
  const float* Wqkv = (const float*)d_in[1];
  const float* Wff  = (const float*)d_in[2];
  const float* bff  = (const float*)d_in[3];
  float* out = (float*)d_out;

  char* ws = (char*)d_ws;
  US* ybf   = (US*)(ws);                 // [0,8M)  y bf16; dead after qkv
  US* ctx   = (US*)(ws);                 // [0,8M)  reuse for ctx
  US* wqkvt = (US*)(ws + (8u << 20));    // [8,14M)
  US* wfft  = (US*)(ws + (14u << 20));   // [14,16M)
  US* qbuf  = (US*)(ws + (16u << 20));   // [16,24M)
  US* kbuf  = (US*)(ws + (24u << 20));   // [24,32M)
  US* vtbuf = (US*)(ws + (40u << 20));   // [40,48M) written directly by qkv

  k_convert<<<MTOT * NINF / 4 / 256, 256, 0, stream>>>(y, ybf, MTOT * NINF / 4);
  k_wtrans<<<dim3(128, 32), dim3(32, 8), 0, stream>>>(Wqkv, Wff, wqkvt, wfft);
  k_gemm_qkv<<<dim3(N3 / 128, MTOT / 128), 256, 0, stream>>>(ybf, wqkvt, qbuf, kbuf, vtbuf);
  k_attn<<<dim3(1024), 256, 0, stream>>>(qbuf, kbuf, vtbuf, ctx);
  k_gemm_out<<<dim3(NOUTF / 64, MTOT / 128), 256, 0, stream>>>(ctx, wfft, bff, out);
}

// Round 7
// 187.005 us; speedup vs baseline: 1.0314x; 1.0314x over previous
//
#include <hip/hip_runtime.h>
#include <stdint.h>

#define NHEADS 16
#define DHEAD 64
#define SEQ 2048
#define BATCH 2
#define NINF 1024
#define NOUTF 1024
#define N3 3072
#define MTOT 4096  // BATCH*SEQ

typedef unsigned short US;
typedef __attribute__((ext_vector_type(8))) short short8;
typedef __attribute__((ext_vector_type(4))) short short4v;
typedef __attribute__((ext_vector_type(4))) float f32x4;

__device__ inline US f2bf(float f) {
  union { float f; unsigned u; } v; v.f = f;
  unsigned r = v.u + 0x7fffu + ((v.u >> 16) & 1u);
  return (US)(r >> 16);
}

__device__ inline f32x4 mfma16(short8 a, short8 b, f32x4 c) {
  return __builtin_amdgcn_mfma_f32_16x16x32_bf16(a, b, c, 0, 0, 0);
}

__device__ inline f32x4 mfma16k16(short4v a, short4v b, f32x4 c) {
  return __builtin_amdgcn_mfma_f32_16x16x16bf16_1k(a, b, c, 0, 0, 0);
}

__device__ inline void async16(const US* g, US* l) {
  __builtin_amdgcn_global_load_lds(
      (const __attribute__((address_space(1))) unsigned int*)g,
      (__attribute__((address_space(3))) unsigned int*)l, 16, 0, 0);
}

// fp32 -> bf16, 4 elements/thread
__global__ void k_convert(const float* __restrict__ src, US* __restrict__ dst, int n4) {
  int i = blockIdx.x * blockDim.x + threadIdx.x;
  if (i >= n4) return;
  float4 v = ((const float4*)src)[i];
  ushort4 o;
  o.x = f2bf(v.x); o.y = f2bf(v.y); o.z = f2bf(v.z); o.w = f2bf(v.w);
  ((ushort4*)dst)[i] = o;
}

// merged weight transpose: Wqkv [1024][3072] and Wff [1024][1024] -> bf16 [C][1024]
__global__ void k_wtrans(const float* __restrict__ Wqkv, const float* __restrict__ Wff,
                         US* __restrict__ dq, US* __restrict__ df) {
  __shared__ float tile[32][33];
  int bxi = blockIdx.x;
  const float* src; US* dst; int C;
  if (bxi < 96) { src = Wqkv; dst = dq; C = N3; }
  else          { src = Wff;  dst = df; C = NOUTF; bxi -= 96; }
  int bx = bxi * 32, by = blockIdx.y * 32;
  int tx = threadIdx.x, ty = threadIdx.y;
  for (int i = 0; i < 32; i += 8)
    tile[ty + i][tx] = src[(size_t)(by + ty + i) * C + bx + tx];
  __syncthreads();
  for (int i = 0; i < 32; i += 8)
    dst[(size_t)(bx + ty + i) * 1024 + by + tx] = f2bf(tile[tx][ty + i]);
}

// ---------------- qkv GEMM v3: pipelined 128x128, specialized loops --------
// v12 fixes v11's regression (54.5us, MfmaUtil 17%, everything idle):
//  1. which-branch HOISTED out of the K-loop: two fully-specialized loops
//     (16 static MFMAs each), single clean body per block.
//  2. depth-2 double-buffered staging + counted s_waitcnt vmcnt(4), raw
//     s_barrier -- the exact loop audited+proven in k_attn v8. The old
//     __syncthreads pair drained vmcnt(0) every one of the 32 K-steps,
//     exposing full global->LDS latency with only 3 blocks/CU of TLP.
// Epilogues kept from v11 (swapped-operand orientation: free transpose):
//  - Q/K: r walks d -> one contiguous uint2 per (i,j), 16 stores/thread.
//  - V: unswapped, r walks s -> writes vtbuf [bh][d][s] DIRECTLY
//    (k_vtrans deleted, -16MB round trip).
__global__ __launch_bounds__(256) void k_gemm_qkv(
    const US* __restrict__ A,   // [MTOT][NINF]
    const US* __restrict__ Bt,  // [N3][NINF]
    US* __restrict__ qbuf, US* __restrict__ kbuf, US* __restrict__ vtbuf) {
  __shared__ US As[2][128 * 32];
  __shared__ US Bs[2][128 * 32];
  int tid = threadIdx.x;
  int wave = tid >> 6, lane = tid & 63, lm = lane & 15, lk = lane >> 4;
  int wm = wave >> 1, wn = wave & 1;
  int mbase = blockIdx.y * 128, nbase = blockIdx.x * 128;
  int which = nbase >> 10;  // 0=q 1=k 2=v (uniform per block)

  f32x4 acc[4][4];
#pragma unroll
  for (int i = 0; i < 4; ++i)
#pragma unroll
    for (int j = 0; j < 4; ++j) acc[i][j] = (f32x4){0.f, 0.f, 0.f, 0.f};

  const US* ga = A + (size_t)(mbase + (tid >> 2)) * NINF + (tid & 3) * 8;
  const US* gb = Bt + (size_t)(nbase + (tid >> 2)) * NINF + (tid & 3) * 8;
  US* la = &As[0][0] + tid * 8;
  US* lb = &Bs[0][0] + tid * 8;

  auto STAGE = [&](int kt, int buf) {
    int ko = kt * 32;
    async16(ga + ko, la + buf * 4096);
    async16(ga + ko + (size_t)64 * NINF, la + buf * 4096 + 2048);
    async16(gb + ko, lb + buf * 4096);
    async16(gb + ko + (size_t)64 * NINF, lb + buf * 4096 + 2048);
  };

  // prologue: tiles 0,1 in flight (NINF/32 = 32 tiles)
  STAGE(0, 0);
  STAGE(1, 1);

  if (which != 2) {
    for (int t = 0; t < 32; ++t) {
      if (t < 31) asm volatile("s_waitcnt vmcnt(4)" ::: "memory");
      else        asm volatile("s_waitcnt vmcnt(0)" ::: "memory");
      __builtin_amdgcn_s_barrier();
      asm volatile("" ::: "memory");
      int buf = t & 1;
      const US* Ab = &As[0][0] + buf * 4096;
      const US* Bb = &Bs[0][0] + buf * 4096;
      short8 a[4], b[4];
#pragma unroll
      for (int i = 0; i < 4; ++i)
        a[i] = *(const short8*)(Ab + (wm * 64 + i * 16 + lm) * 32 + lk * 8);
#pragma unroll
      for (int j = 0; j < 4; ++j)
        b[j] = *(const short8*)(Bb + (wn * 64 + j * 16 + lm) * 32 + lk * 8);
      // swapped: lane holds C[m=..+i*16+lm][n=..+j*16+lk*4+r]
#pragma unroll
      for (int i = 0; i < 4; ++i)
#pragma unroll
        for (int j = 0; j < 4; ++j) acc[i][j] = mfma16(b[j], a[i], acc[i][j]);
      asm volatile("" ::: "memory");
      __builtin_amdgcn_s_barrier();
      asm volatile("" ::: "memory");
      if (t + 2 < 32) STAGE(t + 2, buf);
    }
  } else {
    for (int t = 0; t < 32; ++t) {
      if (t < 31) asm volatile("s_waitcnt vmcnt(4)" ::: "memory");
      else        asm volatile("s_waitcnt vmcnt(0)" ::: "memory");
      __builtin_amdgcn_s_barrier();
      asm volatile("" ::: "memory");
      int buf = t & 1;
      const US* Ab = &As[0][0] + buf * 4096;
      const US* Bb = &Bs[0][0] + buf * 4096;
      short8 a[4], b[4];
#pragma unroll
      for (int i = 0; i < 4; ++i)
        a[i] = *(const short8*)(Ab + (wm * 64 + i * 16 + lm) * 32 + lk * 8);
#pragma unroll
      for (int j = 0; j < 4; ++j)
        b[j] = *(const short8*)(Bb + (wn * 64 + j * 16 + lm) * 32 + lk * 8);
      // unswapped: lane holds C[m=..+i*16+lk*4+r][n=..+j*16+lm]
#pragma unroll
      for (int i = 0; i < 4; ++i)
#pragma unroll
        for (int j = 0; j < 4; ++j) acc[i][j] = mfma16(a[i], b[j], acc[i][j]);
      asm volatile("" ::: "memory");
      __builtin_amdgcn_s_barrier();
      asm volatile("" ::: "memory");
      if (t + 2 < 32) STAGE(t + 2, buf);
    }
  }

  int hh = ((nbase + wn * 64) & 1023) >> 6;  // head of this wave's 64-col block
  if (which != 2) {
    US* dsts = (which == 0) ? qbuf : kbuf;
    float sc = (which == 0) ? 0.18033688011112042f : 1.f;  // log2(e)/8 folded into Q
#pragma unroll
    for (int i = 0; i < 4; ++i) {
      int row = mbase + wm * 64 + i * 16 + lm;
      int bh = (row >> 11) * NHEADS + hh;
      int s = row & (SEQ - 1);
      US* base = dsts + ((size_t)bh * SEQ + s) * DHEAD;
#pragma unroll
      for (int j = 0; j < 4; ++j) {
        int d0 = j * 16 + lk * 4;
        uint32_t lo = (uint32_t)f2bf(acc[i][j][0] * sc) | ((uint32_t)f2bf(acc[i][j][1] * sc) << 16);
        uint32_t hi = (uint32_t)f2bf(acc[i][j][2] * sc) | ((uint32_t)f2bf(acc[i][j][3] * sc) << 16);
        uint2 pv; pv.x = lo; pv.y = hi;
        *(uint2*)(base + d0) = pv;   // 8B contiguous along d
      }
    }
  } else {
    // direct V^T write: vtbuf [bh][d][s], r walks s (contiguous)
#pragma unroll
    for (int j = 0; j < 4; ++j) {
      int d = j * 16 + lm;
#pragma unroll
      for (int i = 0; i < 4; ++i) {
        int row0 = mbase + wm * 64 + i * 16 + lk * 4;
        int bh = (row0 >> 11) * NHEADS + hh;
        int s0 = row0 & (SEQ - 1);
        uint32_t lo = (uint32_t)f2bf(acc[i][j][0]) | ((uint32_t)f2bf(acc[i][j][1]) << 16);
        uint32_t hi = (uint32_t)f2bf(acc[i][j][2]) | ((uint32_t)f2bf(acc[i][j][3]) << 16);
        uint2 pv; pv.x = lo; pv.y = hi;
        *(uint2*)(vtbuf + ((size_t)bh * DHEAD + d) * SEQ + s0) = pv;  // 8B along s
      }
    }
  }
}

// ---------------- attention v8 (best: 45.7us) ----------------
// v9 (full key-split) regressed 64.8; v10 (hybrid 32q x 32k) neutral 46.5 with
// halved conflicts -> LDS throughput proven NOT the critical path. v8 is the
// local optimum of this structure: q-split waves, balanced dispatch rounds,
// depth-2 dbuf + counted vmcnt(4), ones-MFMA rowsums, exp2-domain scores.
__global__ __launch_bounds__(256) void k_attn(
    const US* __restrict__ qbuf, const US* __restrict__ kbuf,
    const US* __restrict__ vtbuf, US* __restrict__ ctx) {
  __shared__ US Ks[2][64 * 64];
  __shared__ US Vs[2][64 * 64];
  int tid = threadIdx.x;
  int w = tid >> 6, lane = tid & 63;
  int lm = lane & 15, lk = lane >> 4;
  int bl = blockIdx.x;            // 1024 blocks
  int xcd = bl & 7, g = bl >> 3;  // g 0..127
  int bh = (g & 3) * 8 + xcd;     // 4 bh per XCD -> working set ~2MB < 4MB L2
  int q4 = g >> 2;                // 0..31
  int rnd = q4 >> 3, qq = q4 & 7;
  int s = (rnd == 0) ? 31 - qq : (rnd == 1) ? qq : (rnd == 2) ? 23 - qq : 8 + qq;
  int qb = s * 64 + w * 16;
  int nt = s + 1;                 // 64-key tiles (can be 1)

  const US* kbase = kbuf + (size_t)bh * SEQ * DHEAD;
  const US* vtb = vtbuf + (size_t)bh * DHEAD * SEQ;
  const US* qr = qbuf + ((size_t)bh * SEQ + qb + lm) * DHEAD + lk * 8;
  short8 qf0 = *(const short8*)(qr);
  short8 qf1 = *(const short8*)(qr + 32);

  // staging: 16 async16 units (8 K + 8 V), 4 per wave, source-side XOR swizzle
  int swz = ((lane & 7) ^ (lane >> 3)) * 8;
  const US* gsrc[4];
  US* ldst[4];
  int step[4];
#pragma unroll
  for (int j = 0; j < 4; ++j) {
    int u = w + 4 * j;
    if (u < 8) {
      gsrc[j] = kbase + (size_t)(u * 8 + (lane >> 3)) * DHEAD + swz;
      ldst[j] = &Ks[0][0] + u * 512 + lane * 8;
      step[j] = 64 * DHEAD;
    } else {
      int i = u - 8;
      gsrc[j] = vtb + (size_t)(i * 8 + (lane >> 3)) * SEQ + swz;
      ldst[j] = &Vs[0][0] + i * 512 + lane * 8;
      step[j] = 64;
    }
  }

  // fragment-read offsets (bytes), swizzle-corrected
  int xorv = lm & 7;
  int ck0 = ((lk) ^ xorv) * 16;
  int ck1 = ((4 + lk) ^ xorv) * 16;
  int cv[4];
#pragma unroll
  for (int kg = 0; kg < 4; ++kg)
    cv[kg] = (((kg * 2 + (lk >> 1)) ^ xorv) * 16) + (lk & 1) * 8;

  f32x4 o[4];
#pragma unroll
  for (int dg = 0; dg < 4; ++dg) o[dg] = (f32x4){0.f, 0.f, 0.f, 0.f};
  f32x4 lacc = (f32x4){0.f, 0.f, 0.f, 0.f};
  const short4v kones = {(short)0x3F80, (short)0x3F80, (short)0x3F80, (short)0x3F80};

  auto body = [&](const char* Kc, const char* Vc, int kg, bool dm) {
    const char* kr = Kc + (kg * 16 + lm) * 128;
    short8 ka0 = *(const short8*)(kr + ck0);
    short8 ka1 = *(const short8*)(kr + ck1);
    f32x4 st = (f32x4){0.f, 0.f, 0.f, 0.f};
    st = mfma16(ka0, qf0, st);
    st = mfma16(ka1, qf1, st);
    uint32_t ue[4];
#pragma unroll
    for (int r = 0; r < 4; ++r) {
      float v = st[r];                       // already in log2 domain (Q pre-scaled)
      if (dm && (lk * 4 + r > lm)) v = -INFINITY;
      union { float f; uint32_t u; } cv2;
      cv2.f = exp2f(v);
      ue[r] = cv2.u + 0x8000u;               // bf16 bias-round; -inf path -> 0x8000 -> +0
    }
    union { short4v s4; uint32_t u[2]; } pk;
    pk.u[0] = __builtin_amdgcn_perm(ue[1], ue[0], 0x07060302u);
    pk.u[1] = __builtin_amdgcn_perm(ue[3], ue[2], 0x07060302u);
    lacc = mfma16k16(kones, pk.s4, lacc);    // row-sums on the MFMA pipe
    const char* vr = Vc + lm * 128 + cv[kg];
#pragma unroll
    for (int dg = 0; dg < 4; ++dg) {
      short4v va = *(const short4v*)(vr + dg * 2048);
      o[dg] = mfma16k16(va, pk.s4, o[dg]);
    }
  };

  // prologue: tile0 -> buf0, (tile1 -> buf1 if it exists)
#pragma unroll
  for (int j = 0; j < 4; ++j) { async16(gsrc[j], ldst[j]); gsrc[j] += step[j]; }
  if (nt > 1) {
#pragma unroll
    for (int j = 0; j < 4; ++j) { async16(gsrc[j], ldst[j] + 4096); gsrc[j] += step[j]; }
  }

  for (int t = 0; t < nt; ++t) {
    if (t + 1 < nt) asm volatile("s_waitcnt vmcnt(4)" ::: "memory");
    else            asm volatile("s_waitcnt vmcnt(0)" ::: "memory");
    __builtin_amdgcn_s_barrier();
    asm volatile("" ::: "memory");
    const char* Kc = (const char*)Ks + (t & 1) * 8192;
    const char* Vc = (const char*)Vs + (t & 1) * 8192;
    if (t < s) {
#pragma unroll
      for (int kg = 0; kg < 4; ++kg) body(Kc, Vc, kg, false);
    } else {
      // diagonal tile: kg > w fully masked, kg == w partially
      for (int kg = 0; kg < w; ++kg) body(Kc, Vc, kg, false);
      body(Kc, Vc, w, true);
    }
    asm volatile("" ::: "memory");
    __builtin_amdgcn_s_barrier();
    asm volatile("" ::: "memory");
    if (t + 2 < nt) {
#pragma unroll
      for (int j = 0; j < 4; ++j) {
        async16(gsrc[j], ldst[j] + (t & 1) * 4096);
        gsrc[j] += step[j];
      }
    }
  }

  // lacc[*] = rowsum for q-row lm (identical across regs/lk groups)
  float inv = 1.f / lacc[0];

  US* crow = ctx + ((size_t)(bh >> 4) * SEQ + qb + lm) * NOUTF + (bh & 15) * DHEAD;
#pragma unroll
  for (int dg = 0; dg < 4; ++dg) {
    union { short4v s4; uint32_t u[2]; } pk;
    pk.u[0] = (uint32_t)f2bf(o[dg][0] * inv) | ((uint32_t)f2bf(o[dg][1] * inv) << 16);
    pk.u[1] = (uint32_t)f2bf(o[dg][2] * inv) | ((uint32_t)f2bf(o[dg][3] * inv) << 16);
    *(short4v*)(crow + dg * 16 + lk * 4) = pk.s4;
  }
}

// ---------------- out GEMM v3: pipelined 128x64, swapped epilogue ----------
// Same depth-2 dbuf + counted vmcnt (3 loads/step -> vmcnt(3)).
__global__ __launch_bounds__(256) void k_gemm_out(
    const US* __restrict__ A, const US* __restrict__ Bt,
    const float* __restrict__ bias, float* __restrict__ out) {
  __shared__ US As[2][128 * 32];
  __shared__ US Bs[2][64 * 32];
  int tid = threadIdx.x;
  int wave = tid >> 6, lane = tid & 63, lm = lane & 15, lk = lane >> 4;
  int mbase = blockIdx.y * 128, nbase = blockIdx.x * 64;

  f32x4 acc[2][4];
#pragma unroll
  for (int i = 0; i < 2; ++i)
#pragma unroll
    for (int j = 0; j < 4; ++j) acc[i][j] = (f32x4){0.f, 0.f, 0.f, 0.f};

  const US* ga = A + (size_t)(mbase + (tid >> 2)) * NOUTF + (tid & 3) * 8;
  const US* gb = Bt + (size_t)(nbase + (tid >> 2)) * NOUTF + (tid & 3) * 8;
  US* la = &As[0][0] + tid * 8;
  US* lb = &Bs[0][0] + tid * 8;

  auto STAGE = [&](int kt, int buf) {
    int ko = kt * 32;
    async16(ga + ko, la + buf * 4096);
    async16(ga + ko + (size_t)64 * NOUTF, la + buf * 4096 + 2048);
    async16(gb + ko, lb + buf * 2048);
  };

  STAGE(0, 0);
  STAGE(1, 1);

  for (int t = 0; t < 32; ++t) {
    if (t < 31) asm volatile("s_waitcnt vmcnt(3)" ::: "memory");
    else        asm volatile("s_waitcnt vmcnt(0)" ::: "memory");
    __builtin_amdgcn_s_barrier();
    asm volatile("" ::: "memory");
    int buf = t & 1;
    const US* Ab = &As[0][0] + buf * 4096;
    const US* Bb = &Bs[0][0] + buf * 2048;
    short8 a[2], b[4];
#pragma unroll
    for (int i = 0; i < 2; ++i)
      a[i] = *(const short8*)(Ab + (wave * 32 + i * 16 + lm) * 32 + lk * 8);
#pragma unroll
    for (int j = 0; j < 4; ++j)
      b[j] = *(const short8*)(Bb + (j * 16 + lm) * 32 + lk * 8);
    // swapped: lane holds out[m=mbase+wave*32+i*16+lm][n=nbase+j*16+lk*4+r]
#pragma unroll
    for (int i = 0; i < 2; ++i)
#pragma unroll
      for (int j = 0; j < 4; ++j) acc[i][j] = mfma16(b[j], a[i], acc[i][j]);
    asm volatile("" ::: "memory");
    __builtin_amdgcn_s_barrier();
    asm volatile("" ::: "memory");
    if (t + 2 < 32) STAGE(t + 2, buf);
  }

#pragma unroll
  for (int j = 0; j < 4; ++j) {
    int n0 = nbase + j * 16 + lk * 4;
    float4 bv = *(const float4*)(bias + n0);
#pragma unroll
    for (int i = 0; i < 2; ++i) {
      int row = mbase + wave * 32 + i * 16 + lm;
      float4 ov;
      ov.x = acc[i][j][0] + bv.x;
      ov.y = acc[i][j][1] + bv.y;
      ov.z = acc[i][j][2] + bv.z;
      ov.w = acc[i][j][3] + bv.w;
      *(float4*)(out + (size_t)row * NOUTF + n0) = ov;  // 16B contiguous
    }
  }
}

extern "C" void kernel_launch(void* const* d_in, const int* in_sizes, int n_in,
                              void* d_out, int out_size, void* d_ws, size_t ws_size,
                              hipStream_t stream) {
  const float* y    = (const float*)d_in[0];
  const float* Wqkv = (const float*)d_in[1];
  const float* Wff  = (const float*)d_in[2];
  const float* bff  = (const float*)d_in[3];
  float* out = (float*)d_out;

  char* ws = (char*)d_ws;
  US* ybf   = (US*)(ws);                 // [0,8M)  y bf16; dead after qkv
  US* ctx   = (US*)(ws);                 // [0,8M)  reuse for ctx
  US* wqkvt = (US*)(ws + (8u << 20));    // [8,14M)
  US* wfft  = (US*)(ws + (14u << 20));   // [14,16M)
  US* qbuf  = (US*)(ws + (16u << 20));   // [16,24M)
  US* kbuf  = (US*)(ws + (24u << 20));   // [24,32M)
  US* vtbuf = (US*)(ws + (40u << 20));   // [40,48M) written directly by qkv

  k_convert<<<MTOT * NINF / 4 / 256, 256, 0, stream>>>(y, ybf, MTOT * NINF / 4);
  k_wtrans<<<dim3(128, 32), dim3(32, 8), 0, stream>>>(Wqkv, Wff, wqkvt, wfft);
  k_gemm_qkv<<<dim3(N3 / 128, MTOT / 128), 256, 0, stream>>>(ybf, wqkvt, qbuf, kbuf, vtbuf);
  k_attn<<<dim3(1024), 256, 0, stream>>>(qbuf, kbuf, vtbuf, ctx);
  k_gemm_out<<<dim3(NOUTF / 64, MTOT / 128), 256, 0, stream>>>(ctx, wfft, bff, out);
}

// Round 8
// 183.000 us; speedup vs baseline: 1.0539x; 1.0219x over previous
//
#include <hip/hip_runtime.h>
#include <stdint.h>

#define NHEADS 16
#define DHEAD 64
#define SEQ 2048
#define BATCH 2
#define NINF 1024
#define NOUTF 1024
#define N3 3072
#define MTOT 4096  // BATCH*SEQ

typedef unsigned short US;
typedef __attribute__((ext_vector_type(8))) short short8;
typedef __attribute__((ext_vector_type(4))) short short4v;
typedef __attribute__((ext_vector_type(4))) float f32x4;

__device__ inline US f2bf(float f) {
  union { float f; unsigned u; } v; v.f = f;
  unsigned r = v.u + 0x7fffu + ((v.u >> 16) & 1u);
  return (US)(r >> 16);
}

__device__ inline f32x4 mfma16(short8 a, short8 b, f32x4 c) {
  return __builtin_amdgcn_mfma_f32_16x16x32_bf16(a, b, c, 0, 0, 0);
}

__device__ inline f32x4 mfma16k16(short4v a, short4v b, f32x4 c) {
  return __builtin_amdgcn_mfma_f32_16x16x16bf16_1k(a, b, c, 0, 0, 0);
}

__device__ inline void async16(const US* g, US* l) {
  __builtin_amdgcn_global_load_lds(
      (const __attribute__((address_space(1))) unsigned int*)g,
      (__attribute__((address_space(3))) unsigned int*)l, 16, 0, 0);
}

// ---------------- fused front kernel: convert + wtrans in one dispatch -----
// blocks [0,4096): y fp32 -> bf16 (float4/thread, exact coverage)
// blocks [4096,8192): weight transpose (Wqkv 96 col-blocks, Wff 32)
__global__ __launch_bounds__(256) void k_pre(
    const float* __restrict__ y, US* __restrict__ ybf,
    const float* __restrict__ Wqkv, const float* __restrict__ Wff,
    US* __restrict__ dq, US* __restrict__ df) {
  __shared__ float tile[32][33];
  int bl = blockIdx.x;
  int tid = threadIdx.x;
  if (bl < 4096) {
    int i = bl * 256 + tid;  // i < 1M = MTOT*NINF/4 exactly
    float4 v = ((const float4*)y)[i];
    ushort4 o;
    o.x = f2bf(v.x); o.y = f2bf(v.y); o.z = f2bf(v.z); o.w = f2bf(v.w);
    ((ushort4*)ybf)[i] = o;
  } else {
    int bl2 = bl - 4096;
    int bxi = bl2 & 127, byi = bl2 >> 7;
    const float* src; US* dst; int C;
    if (bxi < 96) { src = Wqkv; dst = dq; C = N3; }
    else          { src = Wff;  dst = df; C = NOUTF; bxi -= 96; }
    int bx = bxi * 32, by = byi * 32;
    int tx = tid & 31, ty = tid >> 5;
    for (int i = 0; i < 32; i += 8)
      tile[ty + i][tx] = src[(size_t)(by + ty + i) * C + bx + tx];
    __syncthreads();
    for (int i = 0; i < 32; i += 8)
      dst[(size_t)(bx + ty + i) * 1024 + by + tx] = f2bf(tile[tx][ty + i]);
  }
}

// per-bh bf16 transpose: vbuf [bh][2048][64] -> vtbuf [bh][64][2048]
__global__ void k_vtrans(const US* __restrict__ src, US* __restrict__ dst) {
  __shared__ US tile[32][33];
  int bh = blockIdx.z;
  int bx = blockIdx.x * 32;  // d
  int by = blockIdx.y * 32;  // s
  int tx = threadIdx.x, ty = threadIdx.y;
  const US* s0 = src + (size_t)bh * SEQ * DHEAD;
  US* d0 = dst + (size_t)bh * DHEAD * SEQ;
  for (int i = 0; i < 32; i += 8)
    tile[ty + i][tx] = s0[(size_t)(by + ty + i) * DHEAD + bx + tx];
  __syncthreads();
  for (int i = 0; i < 32; i += 8)
    d0[(size_t)(bx + ty + i) * SEQ + by + tx] = tile[tx][ty + i];
}

// ---------------- qkv GEMM v4: original proven loop + uniform swapped body --
// v12 post-mortem: attn's depth-2 vmcnt pipeline HURT here (59.9us) -- qkv
// streams from L3/HBM (~600-900cy) and 16 MFMAs/step can't cover it; the
// original single-buffer 2-sync loop with 3 blocks/CU TLP was <46us. v11's
// regression was the which-branch INSIDE the K-loop, not the epilogue.
// v4 = original loop, UNIFORM swapped mfma(b,a) for all q/k/v (zero branches
// in the loop), uniform vectorized epilogue: r walks the d axis -> one
// contiguous uint2 per fragment into [bh][s][d] (16 stores/thread vs 64).
// V goes back to vbuf + k_vtrans (v11's scattered V^T stores deleted).
__global__ __launch_bounds__(256) void k_gemm_qkv(
    const US* __restrict__ A,   // [MTOT][NINF]
    const US* __restrict__ Bt,  // [N3][NINF]
    US* __restrict__ qbuf, US* __restrict__ kbuf, US* __restrict__ vbuf) {
  __shared__ US As[128 * 32];
  __shared__ US Bs[128 * 32];
  int tid = threadIdx.x;
  int wave = tid >> 6, lane = tid & 63, lm = lane & 15, lk = lane >> 4;
  int wm = wave >> 1, wn = wave & 1;
  int mbase = blockIdx.y * 128, nbase = blockIdx.x * 128;

  f32x4 acc[4][4];
#pragma unroll
  for (int i = 0; i < 4; ++i)
#pragma unroll
    for (int j = 0; j < 4; ++j) acc[i][j] = (f32x4){0.f, 0.f, 0.f, 0.f};

  const US* ga = A + (size_t)(mbase + (tid >> 2)) * NINF + (tid & 3) * 8;
  const US* gb = Bt + (size_t)(nbase + (tid >> 2)) * NINF + (tid & 3) * 8;
  US* la = As + tid * 8;
  US* lb = Bs + tid * 8;

  for (int kt = 0; kt < NINF / 32; ++kt) {
    int ko = kt * 32;
    async16(ga + ko, la);
    async16(ga + ko + (size_t)64 * NINF, la + 64 * 32);
    async16(gb + ko, lb);
    async16(gb + ko + (size_t)64 * NINF, lb + 64 * 32);
    __syncthreads();
    short8 a[4], b[4];
#pragma unroll
    for (int i = 0; i < 4; ++i)
      a[i] = *(const short8*)(As + (wm * 64 + i * 16 + lm) * 32 + lk * 8);
#pragma unroll
    for (int j = 0; j < 4; ++j)
      b[j] = *(const short8*)(Bs + (wn * 64 + j * 16 + lm) * 32 + lk * 8);
    // swapped: lane holds C[m=mbase+wm*64+i*16+lm][n=nbase+wn*64+j*16+lk*4+r]
#pragma unroll
    for (int i = 0; i < 4; ++i)
#pragma unroll
      for (int j = 0; j < 4; ++j) acc[i][j] = mfma16(b[j], a[i], acc[i][j]);
    __syncthreads();
  }

  int which = nbase >> 10;  // 0=q 1=k 2=v (uniform per block)
  US* dsts = (which == 0) ? qbuf : (which == 1) ? kbuf : vbuf;
  float sc = (which == 0) ? 0.18033688011112042f : 1.f;  // log2(e)/8 folded into Q
  int hh = ((nbase + wn * 64) & 1023) >> 6;  // head of this wave's 64-col block
#pragma unroll
  for (int i = 0; i < 4; ++i) {
    int row = mbase + wm * 64 + i * 16 + lm;
    int bh = (row >> 11) * NHEADS + hh;
    int s = row & (SEQ - 1);
    US* base = dsts + ((size_t)bh * SEQ + s) * DHEAD;
#pragma unroll
    for (int j = 0; j < 4; ++j) {
      int d0 = j * 16 + lk * 4;
      uint32_t lo = (uint32_t)f2bf(acc[i][j][0] * sc) | ((uint32_t)f2bf(acc[i][j][1] * sc) << 16);
      uint32_t hi = (uint32_t)f2bf(acc[i][j][2] * sc) | ((uint32_t)f2bf(acc[i][j][3] * sc) << 16);
      uint2 pv; pv.x = lo; pv.y = hi;
      *(uint2*)(base + d0) = pv;   // 8B contiguous along d
    }
  }
}

// ---------------- attention v8 (best: 45.7us, unchanged) ----------------
__global__ __launch_bounds__(256) void k_attn(
    const US* __restrict__ qbuf, const US* __restrict__ kbuf,
    const US* __restrict__ vtbuf, US* __restrict__ ctx) {
  __shared__ US Ks[2][64 * 64];
  __shared__ US Vs[2][64 * 64];
  int tid = threadIdx.x;
  int w = tid >> 6, lane = tid & 63;
  int lm = lane & 15, lk = lane >> 4;
  int bl = blockIdx.x;            // 1024 blocks
  int xcd = bl & 7, g = bl >> 3;  // g 0..127
  int bh = (g & 3) * 8 + xcd;     // 4 bh per XCD -> working set ~2MB < 4MB L2
  int q4 = g >> 2;                // 0..31
  int rnd = q4 >> 3, qq = q4 & 7;
  int s = (rnd == 0) ? 31 - qq : (rnd == 1) ? qq : (rnd == 2) ? 23 - qq : 8 + qq;
  int qb = s * 64 + w * 16;
  int nt = s + 1;                 // 64-key tiles (can be 1)

  const US* kbase = kbuf + (size_t)bh * SEQ * DHEAD;
  const US* vtb = vtbuf + (size_t)bh * DHEAD * SEQ;
  const US* qr = qbuf + ((size_t)bh * SEQ + qb + lm) * DHEAD + lk * 8;
  short8 qf0 = *(const short8*)(qr);
  short8 qf1 = *(const short8*)(qr + 32);

  // staging: 16 async16 units (8 K + 8 V), 4 per wave, source-side XOR swizzle
  int swz = ((lane & 7) ^ (lane >> 3)) * 8;
  const US* gsrc[4];
  US* ldst[4];
  int step[4];
#pragma unroll
  for (int j = 0; j < 4; ++j) {
    int u = w + 4 * j;
    if (u < 8) {
      gsrc[j] = kbase + (size_t)(u * 8 + (lane >> 3)) * DHEAD + swz;
      ldst[j] = &Ks[0][0] + u * 512 + lane * 8;
      step[j] = 64 * DHEAD;
    } else {
      int i = u - 8;
      gsrc[j] = vtb + (size_t)(i * 8 + (lane >> 3)) * SEQ + swz;
      ldst[j] = &Vs[0][0] + i * 512 + lane * 8;
      step[j] = 64;
    }
  }

  // fragment-read offsets (bytes), swizzle-corrected
  int xorv = lm & 7;
  int ck0 = ((lk) ^ xorv) * 16;
  int ck1 = ((4 + lk) ^ xorv) * 16;
  int cv[4];
#pragma unroll
  for (int kg = 0; kg < 4; ++kg)
    cv[kg] = (((kg * 2 + (lk >> 1)) ^ xorv) * 16) + (lk & 1) * 8;

  f32x4 o[4];
#pragma unroll
  for (int dg = 0; dg < 4; ++dg) o[dg] = (f32x4){0.f, 0.f, 0.f, 0.f};
  f32x4 lacc = (f32x4){0.f, 0.f, 0.f, 0.f};
  const short4v kones = {(short)0x3F80, (short)0x3F80, (short)0x3F80, (short)0x3F80};

  auto body = [&](const char* Kc, const char* Vc, int kg, bool dm) {
    const char* kr = Kc + (kg * 16 + lm) * 128;
    short8 ka0 = *(const short8*)(kr + ck0);
    short8 ka1 = *(const short8*)(kr + ck1);
    f32x4 st = (f32x4){0.f, 0.f, 0.f, 0.f};
    st = mfma16(ka0, qf0, st);
    st = mfma16(ka1, qf1, st);
    uint32_t ue[4];
#pragma unroll
    for (int r = 0; r < 4; ++r) {
      float v = st[r];                       // already in log2 domain (Q pre-scaled)
      if (dm && (lk * 4 + r > lm)) v = -INFINITY;
      union { float f; uint32_t u; } cv2;
      cv2.f = exp2f(v);
      ue[r] = cv2.u + 0x8000u;               // bf16 bias-round; -inf path -> 0x8000 -> +0
    }
    union { short4v s4; uint32_t u[2]; } pk;
    pk.u[0] = __builtin_amdgcn_perm(ue[1], ue[0], 0x07060302u);
    pk.u[1] = __builtin_amdgcn_perm(ue[3], ue[2], 0x07060302u);
    lacc = mfma16k16(kones, pk.s4, lacc);    // row-sums on the MFMA pipe
    const char* vr = Vc + lm * 128 + cv[kg];
#pragma unroll
    for (int dg = 0; dg < 4; ++dg) {
      short4v va = *(const short4v*)(vr + dg * 2048);
      o[dg] = mfma16k16(va, pk.s4, o[dg]);
    }
  };

  // prologue: tile0 -> buf0, (tile1 -> buf1 if it exists)
#pragma unroll
  for (int j = 0; j < 4; ++j) { async16(gsrc[j], ldst[j]); gsrc[j] += step[j]; }
  if (nt > 1) {
#pragma unroll
    for (int j = 0; j < 4; ++j) { async16(gsrc[j], ldst[j] + 4096); gsrc[j] += step[j]; }
  }

  for (int t = 0; t < nt; ++t) {
    if (t + 1 < nt) asm volatile("s_waitcnt vmcnt(4)" ::: "memory");
    else            asm volatile("s_waitcnt vmcnt(0)" ::: "memory");
    __builtin_amdgcn_s_barrier();
    asm volatile("" ::: "memory");
    const char* Kc = (const char*)Ks + (t & 1) * 8192;
    const char* Vc = (const char*)Vs + (t & 1) * 8192;
    if (t < s) {
#pragma unroll
      for (int kg = 0; kg < 4; ++kg) body(Kc, Vc, kg, false);
    } else {
      // diagonal tile: kg > w fully masked, kg == w partially
      for (int kg = 0; kg < w; ++kg) body(Kc, Vc, kg, false);
      body(Kc, Vc, w, true);
    }
    asm volatile("" ::: "memory");
    __builtin_amdgcn_s_barrier();
    asm volatile("" ::: "memory");
    if (t + 2 < nt) {
#pragma unroll
      for (int j = 0; j < 4; ++j) {
        async16(gsrc[j], ldst[j] + (t & 1) * 4096);
        gsrc[j] += step[j];
      }
    }
  }

  // lacc[*] = rowsum for q-row lm (identical across regs/lk groups)
  float inv = 1.f / lacc[0];

  US* crow = ctx + ((size_t)(bh >> 4) * SEQ + qb + lm) * NOUTF + (bh & 15) * DHEAD;
#pragma unroll
  for (int dg = 0; dg < 4; ++dg) {
    union { short4v s4; uint32_t u[2]; } pk;
    pk.u[0] = (uint32_t)f2bf(o[dg][0] * inv) | ((uint32_t)f2bf(o[dg][1] * inv) << 16);
    pk.u[1] = (uint32_t)f2bf(o[dg][2] * inv) | ((uint32_t)f2bf(o[dg][3] * inv) << 16);
    *(short4v*)(crow + dg * 16 + lk * 4) = pk.s4;
  }
}

// ---------------- out GEMM v4: 64x64 tile for 4 blocks/CU TLP --------------
// v13: old 128x64 grid was 512 blocks = 2 blocks/CU (TLP-starved, the v7
// lesson). 64x64 tile -> 1024 blocks = 4/CU. Simple proven sync loop,
// swapped epilogue (r walks n), float4 stores with fused bias.
__global__ __launch_bounds__(256) void k_gemm_out(
    const US* __restrict__ A, const US* __restrict__ Bt,
    const float* __restrict__ bias, float* __restrict__ out) {
  __shared__ US As[64 * 32];
  __shared__ US Bs[64 * 32];
  int tid = threadIdx.x;
  int wave = tid >> 6, lane = tid & 63, lm = lane & 15, lk = lane >> 4;
  int wm = wave >> 1, wn = wave & 1;
  int mbase = blockIdx.y * 64, nbase = blockIdx.x * 64;

  f32x4 acc[2][2];
#pragma unroll
  for (int i = 0; i < 2; ++i)
#pragma unroll
    for (int j = 0; j < 2; ++j) acc[i][j] = (f32x4){0.f, 0.f, 0.f, 0.f};

  const US* ga = A + (size_t)(mbase + (tid >> 2)) * NOUTF + (tid & 3) * 8;
  const US* gb = Bt + (size_t)(nbase + (tid >> 2)) * NOUTF + (tid & 3) * 8;
  US* la = As + tid * 8;
  US* lb = Bs + tid * 8;

  for (int kt = 0; kt < NOUTF / 32; ++kt) {
    int ko = kt * 32;
    async16(ga + ko, la);
    async16(gb + ko, lb);
    __syncthreads();
    short8 a[2], b[2];
#pragma unroll
    for (int i = 0; i < 2; ++i)
      a[i] = *(const short8*)(As + (wm * 32 + i * 16 + lm) * 32 + lk * 8);
#pragma unroll
    for (int j = 0; j < 2; ++j)
      b[j] = *(const short8*)(Bs + (wn * 32 + j * 16 + lm) * 32 + lk * 8);
    // swapped: lane holds out[m=mbase+wm*32+i*16+lm][n=nbase+wn*32+j*16+lk*4+r]
#pragma unroll
    for (int i = 0; i < 2; ++i)
#pragma unroll
      for (int j = 0; j < 2; ++j) acc[i][j] = mfma16(b[j], a[i], acc[i][j]);
    __syncthreads();
  }

#pragma unroll
  for (int j = 0; j < 2; ++j) {
    int n0 = nbase + wn * 32 + j * 16 + lk * 4;
    float4 bv = *(const float4*)(bias + n0);
#pragma unroll
    for (int i = 0; i < 2; ++i) {
      int row = mbase + wm * 32 + i * 16 + lm;
      float4 ov;
      ov.x = acc[i][j][0] + bv.x;
      ov.y = acc[i][j][1] + bv.y;
      ov.z = acc[i][j][2] + bv.z;
      ov.w = acc[i][j][3] + bv.w;
      *(float4*)(out + (size_t)row * NOUTF + n0) = ov;  // 16B contiguous
    }
  }
}

extern "C" void kernel_launch(void* const* d_in, const int* in_sizes, int n_in,
                              void* d_out, int out_size, void* d_ws, size_t ws_size,
                              hipStream_t stream) {
  const float* y    = (const float*)d_in[0];
  const float* Wqkv = (const float*)d_in[1];
  const float* Wff  = (const float*)d_in[2];
  const float* bff  = (const float*)d_in[3];
  float* out = (float*)d_out;

  char* ws = (char*)d_ws;
  US* ybf   = (US*)(ws);                 // [0,8M)  y bf16; dead after qkv
  US* ctx   = (US*)(ws);                 // [0,8M)  reuse for ctx
  US* wqkvt = (US*)(ws + (8u << 20));    // [8,14M)
  US* wfft  = (US*)(ws + (14u << 20));   // [14,16M)
  US* qbuf  = (US*)(ws + (16u << 20));   // [16,24M)
  US* kbuf  = (US*)(ws + (24u << 20));   // [24,32M)
  US* vbuf  = (US*)(ws + (32u << 20));   // [32,40M) dead after vtrans
  US* vtbuf = (US*)(ws + (40u << 20));   // [40,48M)

  k_pre<<<dim3(8192), 256, 0, stream>>>(y, ybf, Wqkv, Wff, wqkvt, wfft);
  k_gemm_qkv<<<dim3(N3 / 128, MTOT / 128), 256, 0, stream>>>(ybf, wqkvt, qbuf, kbuf, vbuf);
  k_vtrans<<<dim3(DHEAD / 32, SEQ / 32, BATCH * NHEADS), dim3(32, 8), 0, stream>>>(vbuf, vtbuf);
  k_attn<<<dim3(1024), 256, 0, stream>>>(qbuf, kbuf, vtbuf, ctx);
  k_gemm_out<<<dim3(NOUTF / 64, MTOT / 64), 256, 0, stream>>>(ctx, wfft, bff, out);
}